// Round 9
// baseline (566.989 us; speedup 1.0000x reference)
//
#include <hip/hip_runtime.h>
#include <hip/hip_cooperative_groups.h>
#include <math.h>

#define NHEAD 8
#define NPT 4
#define HDIM 32
#define IMG 64      // H = W = 64
#define CDIM 256
#define NQ 4096
#define BATCH 8
#define MTOT (BATCH * NQ)   // 32768

namespace cg = cooperative_groups;

typedef __attribute__((ext_vector_type(8))) short bf16x8;
typedef __attribute__((ext_vector_type(4))) float f32x4;

__device__ __forceinline__ unsigned short f2b(float f) {
    union { float f; unsigned u; } v; v.f = f;
    unsigned r = (v.u + 0x7FFFu + ((v.u >> 16) & 1u)) >> 16;
    return (unsigned short)r;
}
__device__ __forceinline__ float b2f(unsigned short u) {
    union { unsigned u; float f; } v; v.u = ((unsigned)u) << 16;
    return v.f;
}

// XOR swizzle for [128][64]-ushort tiles (8 chunks of 16B per row).
#define SWZ(row, col)   ((col) ^ (((row) & 7) << 3))

// Async global->LDS, 16B per lane; dest = wave-uniform base + lane*16.
__device__ __forceinline__ void gload16(const void* src, void* ldsbase) {
    __builtin_amdgcn_global_load_lds(
        (const __attribute__((address_space(1))) void*)src,
        (__attribute__((address_space(3))) void*)ldsbase, 16, 0, 0);
}

struct MP {
    const float* query; const float* value; const float* refp;
    const float* W_off; const float* b_off;
    const float* W_attn; const float* b_attn;
    const float* W_val; const float* b_val;
    const float* W_out; const float* b_out;
    unsigned short* projv; unsigned short* sampled; float* lin;
    unsigned short* Wv_t; unsigned short* Wo_t;
    unsigned short* Wl_h; unsigned short* Wl_l;
    float* bias_lin; float* out;
};

// ---------------------------------------------------------------------------
// P0: weight prep (65536 worker threads)
// ---------------------------------------------------------------------------
__device__ __forceinline__ void body_cvtw(int gt, const MP& P)
{
    int n = gt & 255, k = gt >> 8;
    P.Wv_t[n * 256 + k] = f2b(P.W_val[k * 256 + n]);
    P.Wo_t[n * 256 + k] = f2b(P.W_out[k * 256 + n]);
    if (gt < 128 * 256) {
        int nn = gt >> 8;
        int kk = gt & 255;
        float v = (nn < 64) ? P.W_off[kk * 64 + nn]
                : (nn < 96) ? P.W_attn[kk * 32 + (nn - 64)] : 0.f;
        unsigned short hi = f2b(v);
        unsigned short lo = f2b(v - b2f(hi));
        P.Wl_h[nn * 256 + kk] = hi;
        P.Wl_l[nn * 256 + kk] = lo;
    }
    if (gt < 128)
        P.bias_lin[gt] = (gt < 64) ? P.b_off[gt] : (gt < 96) ? P.b_attn[gt - 64] : 0.f;
}

// ---------------------------------------------------------------------------
// P1a: value projection tile (A = f32 value reg-staged cvt; B = Wv_t gload)
// ---------------------------------------------------------------------------
__device__ void body_val(char* smem, int gm, int gn, const MP& P, int tid)
{
    unsigned short (*As)[64] = (unsigned short(*)[64])smem;
    unsigned short (*Bs)[64] = (unsigned short(*)[64])(smem + 16384);
    const int lane = tid & 63, wid = tid >> 6;
    const int wr = (wid >> 1) * 64, wc = (wid & 1) * 64;
    const int l15 = lane & 15, lk = (lane >> 4) * 8;
    const int rl = lane >> 3, ch = (lane & 7) ^ rl;

    f32x4 acc[4][4];
    #pragma unroll
    for (int m = 0; m < 4; ++m)
        #pragma unroll
        for (int n = 0; n < 4; ++n)
            #pragma unroll
            for (int r = 0; r < 4; ++r) acc[m][n][r] = 0.f;

    for (int k0 = 0; k0 < 256; k0 += 64) {
        #pragma unroll
        for (int it = 0; it < 4; ++it) {
            const int br = it * 32 + wid * 8;
            gload16(&P.Wv_t[(size_t)(gn + br + rl) * 256 + k0 + ch * 8], &Bs[br][0]);
        }
        #pragma unroll
        for (int it = 0; it < 4; ++it) {
            const int chunk = it * 256 + tid;
            const int row = chunk >> 3;
            const int kc  = (chunk & 7) << 3;
            const float4* src = (const float4*)&P.value[(size_t)(gm + row) * 256 + k0 + kc];
            const float4 a = src[0], b = src[1];
            float f[8] = {a.x, a.y, a.z, a.w, b.x, b.y, b.z, b.w};
            unsigned short h[8];
            #pragma unroll
            for (int j = 0; j < 8; ++j) h[j] = f2b(f[j]);
            *(uint4*)&As[row][SWZ(row, kc)] = *(const uint4*)h;
        }
        __syncthreads();

        #pragma unroll
        for (int kk = 0; kk < 64; kk += 32) {
            bf16x8 a[4], b[4];
            #pragma unroll
            for (int m = 0; m < 4; ++m) {
                const int r = wr + m * 16 + l15;
                a[m] = *(const bf16x8*)&As[r][SWZ(r, kk + lk)];
            }
            #pragma unroll
            for (int n = 0; n < 4; ++n) {
                const int r = wc + n * 16 + l15;
                b[n] = *(const bf16x8*)&Bs[r][SWZ(r, kk + lk)];
            }
            #pragma unroll
            for (int m = 0; m < 4; ++m)
                #pragma unroll
                for (int n = 0; n < 4; ++n)
                    acc[m][n] = __builtin_amdgcn_mfma_f32_16x16x32_bf16(a[m], b[n], acc[m][n], 0, 0, 0);
        }
        __syncthreads();
    }

    const int cr = (lane >> 4) * 4;
    #pragma unroll
    for (int n = 0; n < 4; ++n) {
        const int col = gn + wc + n * 16 + l15;
        const float bv = P.b_val[col];
        #pragma unroll
        for (int m = 0; m < 4; ++m)
            #pragma unroll
            for (int r = 0; r < 4; ++r) {
                const int row = gm + wr + m * 16 + cr + r;
                P.projv[(size_t)row * 256 + col] = f2b(acc[m][n][r] + bv);
            }
    }
}

// ---------------------------------------------------------------------------
// P1b: offset/attn logits tile (BK=32; A = f32 query gload'd, hi/lo split at
// fragment read; B = Wl_h/Wl_l gload'd). 3-term split precision.
// ---------------------------------------------------------------------------
__device__ void body_lin(char* smem, int gm, const MP& P, int tid)
{
    float (*Aq)[32] = (float(*)[32])smem;                              // 16 KB
    unsigned short (*Bh)[32] = (unsigned short(*)[32])(smem + 16384);  // 8 KB
    unsigned short (*Bl)[32] = (unsigned short(*)[32])(smem + 24576);  // 8 KB
    const int lane = tid & 63, wid = tid >> 6;
    const int wr = (wid >> 1) * 64, wc = (wid & 1) * 64;
    const int l15 = lane & 15, lk = (lane >> 4) * 8;
    const int rla = lane >> 3;                 // A: 8 rows x 8 chunks (16B=4 f32)
    const int ca  = (lane & 7) ^ rla;
    const int rsb = lane >> 2;                 // B: 16 rows x 4 chunks (16B=8 us)
    const int cb  = (lane & 3) ^ (rsb & 3);

    f32x4 acc[4][4];
    #pragma unroll
    for (int m = 0; m < 4; ++m)
        #pragma unroll
        for (int n = 0; n < 4; ++n)
            #pragma unroll
            for (int r = 0; r < 4; ++r) acc[m][n][r] = 0.f;

    for (int k0 = 0; k0 < 256; k0 += 32) {
        #pragma unroll
        for (int i = 0; i < 4; ++i) {
            const int ar = wid * 32 + i * 8;
            gload16(&P.query[(size_t)(gm + ar + rla) * 256 + k0 + ca * 4], &Aq[ar][0]);
        }
        #pragma unroll
        for (int i = 0; i < 2; ++i) {
            const int br = wid * 32 + i * 16;
            gload16(&P.Wl_h[(size_t)(br + rsb) * 256 + k0 + cb * 8], &Bh[br][0]);
            gload16(&P.Wl_l[(size_t)(br + rsb) * 256 + k0 + cb * 8], &Bl[br][0]);
        }
        __syncthreads();

        bf16x8 ah[4], al[4];
        #pragma unroll
        for (int m = 0; m < 4; ++m) {
            const int r = wr + m * 16 + l15;
            const int c0 = ((lk >> 2) ^ (r & 7)) << 2;
            const int c1 = (((lk >> 2) + 1) ^ (r & 7)) << 2;
            const f32x4 qa = *(const f32x4*)&Aq[r][c0];
            const f32x4 qb = *(const f32x4*)&Aq[r][c1];
            float f[8] = {qa.x, qa.y, qa.z, qa.w, qb.x, qb.y, qb.z, qb.w};
            unsigned short h[8], l[8];
            #pragma unroll
            for (int j = 0; j < 8; ++j) {
                h[j] = f2b(f[j]);
                l[j] = f2b(f[j] - b2f(h[j]));
            }
            ah[m] = *(const bf16x8*)h;
            al[m] = *(const bf16x8*)l;
        }

        const int nN = (wc == 0) ? 4 : 2;
        #pragma unroll
        for (int n = 0; n < 4; ++n) {
            if (n >= nN) break;
            const int r = wc + n * 16 + l15;
            const int c = ((lk >> 3) ^ (r & 3)) << 3;
            const bf16x8 bh = *(const bf16x8*)&Bh[r][c];
            const bf16x8 bl = *(const bf16x8*)&Bl[r][c];
            #pragma unroll
            for (int m = 0; m < 4; ++m) {
                acc[m][n] = __builtin_amdgcn_mfma_f32_16x16x32_bf16(ah[m], bh, acc[m][n], 0, 0, 0);
                acc[m][n] = __builtin_amdgcn_mfma_f32_16x16x32_bf16(ah[m], bl, acc[m][n], 0, 0, 0);
                acc[m][n] = __builtin_amdgcn_mfma_f32_16x16x32_bf16(al[m], bh, acc[m][n], 0, 0, 0);
            }
        }
        __syncthreads();
    }

    const int cr = (lane >> 4) * 4;
    #pragma unroll
    for (int n = 0; n < 4; ++n) {
        const int col = wc + n * 16 + l15;
        if (col < 96) {
            const float bv = P.bias_lin[col];
            #pragma unroll
            for (int m = 0; m < 4; ++m)
                #pragma unroll
                for (int r = 0; r < 4; ++r) {
                    const int row = gm + wr + m * 16 + cr + r;
                    P.lin[(size_t)row * 96 + col] = acc[m][n][r] + bv;
                }
        }
    }
}

// ---------------------------------------------------------------------------
// P2: gather task (8 queries). Leading barrier protects LDS reuse.
// ---------------------------------------------------------------------------
__device__ void body_gather(char* smem, int b, int bn0, const MP& P, int t)
{
    float4*   s_w  = (float4*)smem;            // [8][32]
    unsigned* s_xy = (unsigned*)(smem + 4096); // [8][32]

    __syncthreads();
    {
        const int sub = t >> 5;        // 0..7
        const int q = t & 31;          // h*4 + p
        const int h = q >> 2;
        const int p = q & 3;
        const int bn = bn0 + sub;
        const float2 rp = *(const float2*)&P.refp[(size_t)bn * 2];
        const float2 ol = *(const float2*)&P.lin[(size_t)bn * 96 + h * 8 + p * 2];
        const float al  = P.lin[(size_t)bn * 96 + 64 + q];

        float mx = al;
        mx = fmaxf(mx, __shfl_xor(mx, 1));
        mx = fmaxf(mx, __shfl_xor(mx, 2));
        float e = expf(al - mx);
        float s = e;
        s += __shfl_xor(s, 1);
        s += __shfl_xor(s, 2);
        const float aw = e / s;

        const float lx = fminf(fmaxf(rp.x + tanhf(ol.x) * 0.5f, 0.f), 1.f);
        const float ly = fminf(fmaxf(rp.y + tanhf(ol.y) * 0.5f, 0.f), 1.f);
        const float x = lx * (float)IMG - 0.5f;
        const float y = ly * (float)IMG - 0.5f;
        const float x0f = floorf(x), y0f = floorf(y);
        const int x0 = (int)x0f, y0 = (int)y0f;
        const float wx1 = x - x0f, wx0 = 1.f - wx1;
        const float wy1 = y - y0f, wy0 = 1.f - wy1;
        const bool vx0 = (x0 >= 0), vx1 = (x0 + 1 < IMG);
        const bool vy0 = (y0 >= 0), vy1 = (y0 + 1 < IMG);
        float4 w;
        w.x = (vx0 && vy0) ? wx0 * wy0 * aw : 0.f;
        w.y = (vx1 && vy0) ? wx1 * wy0 * aw : 0.f;
        w.z = (vx0 && vy1) ? wx0 * wy1 * aw : 0.f;
        w.w = (vx1 && vy1) ? wx1 * wy1 * aw : 0.f;
        const int x0c = min(max(x0, 0), IMG - 1), x1c = min(max(x0 + 1, 0), IMG - 1);
        const int y0c = min(max(y0, 0), IMG - 1), y1c = min(max(y0 + 1, 0), IMG - 1);
        s_w[sub * 32 + q] = w;
        s_xy[sub * 32 + q] = (unsigned)x0c | ((unsigned)x1c << 8)
                           | ((unsigned)y0c << 16) | ((unsigned)y1c << 24);
    }
    __syncthreads();

    const int l = t & 63;
    const int h2 = l >> 3;
    const int cp = l & 7;
    const unsigned short* vbase = P.projv + ((size_t)b << 20) + h2 * HDIM + cp * 4;

    #pragma unroll
    for (int pass = 0; pass < 2; ++pass) {
        const int sub = (t >> 6) + pass * 4;
        const int bn = bn0 + sub;

        float a0 = 0.f, a1 = 0.f, a2 = 0.f, a3 = 0.f;
        #pragma unroll
        for (int p = 0; p < 4; ++p) {
            const float4 w = s_w[sub * 32 + h2 * 4 + p];
            const unsigned xy = s_xy[sub * 32 + h2 * 4 + p];
            const int x0 = xy & 255, x1 = (xy >> 8) & 255;
            const int y0 = (xy >> 16) & 255, y1 = xy >> 24;
            const uint2 u00 = *(const uint2*)&vbase[(((y0 << 6) + x0) << 8)];
            const uint2 u01 = *(const uint2*)&vbase[(((y0 << 6) + x1) << 8)];
            const uint2 u10 = *(const uint2*)&vbase[(((y1 << 6) + x0) << 8)];
            const uint2 u11 = *(const uint2*)&vbase[(((y1 << 6) + x1) << 8)];
            a0 += w.x * b2f((unsigned short)(u00.x & 0xffff)) + w.y * b2f((unsigned short)(u01.x & 0xffff))
                + w.z * b2f((unsigned short)(u10.x & 0xffff)) + w.w * b2f((unsigned short)(u11.x & 0xffff));
            a1 += w.x * b2f((unsigned short)(u00.x >> 16)) + w.y * b2f((unsigned short)(u01.x >> 16))
                + w.z * b2f((unsigned short)(u10.x >> 16)) + w.w * b2f((unsigned short)(u11.x >> 16));
            a2 += w.x * b2f((unsigned short)(u00.y & 0xffff)) + w.y * b2f((unsigned short)(u01.y & 0xffff))
                + w.z * b2f((unsigned short)(u10.y & 0xffff)) + w.w * b2f((unsigned short)(u11.y & 0xffff));
            a3 += w.x * b2f((unsigned short)(u00.y >> 16)) + w.y * b2f((unsigned short)(u01.y >> 16))
                + w.z * b2f((unsigned short)(u10.y >> 16)) + w.w * b2f((unsigned short)(u11.y >> 16));
        }
        uint2 outp;
        outp.x = (unsigned)f2b(a0) | ((unsigned)f2b(a1) << 16);
        outp.y = (unsigned)f2b(a2) | ((unsigned)f2b(a3) << 16);
        *(uint2*)&P.sampled[(size_t)bn * 256 + h2 * HDIM + cp * 4] = outp;
    }
}

// ---------------------------------------------------------------------------
// P3: output projection tile (both operands gload'd)
// ---------------------------------------------------------------------------
__device__ void body_out(char* smem, int gm, int gn, const MP& P, int tid)
{
    unsigned short (*As)[64] = (unsigned short(*)[64])smem;
    unsigned short (*Bs)[64] = (unsigned short(*)[64])(smem + 16384);
    const int lane = tid & 63, wid = tid >> 6;
    const int wr = (wid >> 1) * 64, wc = (wid & 1) * 64;
    const int l15 = lane & 15, lk = (lane >> 4) * 8;
    const int rl = lane >> 3, ch = (lane & 7) ^ rl;

    f32x4 acc[4][4];
    #pragma unroll
    for (int m = 0; m < 4; ++m)
        #pragma unroll
        for (int n = 0; n < 4; ++n)
            #pragma unroll
            for (int r = 0; r < 4; ++r) acc[m][n][r] = 0.f;

    for (int k0 = 0; k0 < 256; k0 += 64) {
        #pragma unroll
        for (int it = 0; it < 4; ++it) {
            const int br = it * 32 + wid * 8;
            gload16(&P.Wo_t[(size_t)(gn + br + rl) * 256 + k0 + ch * 8], &Bs[br][0]);
            gload16(&P.sampled[(size_t)(gm + br + rl) * 256 + k0 + ch * 8], &As[br][0]);
        }
        __syncthreads();

        #pragma unroll
        for (int kk = 0; kk < 64; kk += 32) {
            bf16x8 a[4], b[4];
            #pragma unroll
            for (int m = 0; m < 4; ++m) {
                const int r = wr + m * 16 + l15;
                a[m] = *(const bf16x8*)&As[r][SWZ(r, kk + lk)];
            }
            #pragma unroll
            for (int n = 0; n < 4; ++n) {
                const int r = wc + n * 16 + l15;
                b[n] = *(const bf16x8*)&Bs[r][SWZ(r, kk + lk)];
            }
            #pragma unroll
            for (int m = 0; m < 4; ++m)
                #pragma unroll
                for (int n = 0; n < 4; ++n)
                    acc[m][n] = __builtin_amdgcn_mfma_f32_16x16x32_bf16(a[m], b[n], acc[m][n], 0, 0, 0);
        }
        __syncthreads();
    }

    const int cr = (lane >> 4) * 4;
    #pragma unroll
    for (int n = 0; n < 4; ++n) {
        const int col = gn + wc + n * 16 + l15;
        const float bv = P.b_out[col];
        #pragma unroll
        for (int m = 0; m < 4; ++m)
            #pragma unroll
            for (int r = 0; r < 4; ++r) {
                const int row = gm + wr + m * 16 + cr + r;
                P.out[(size_t)row * 256 + col] = acc[m][n][r] + bv;
            }
    }
}

// ---------------------------------------------------------------------------
// Cooperative mega-kernel: 768 blocks (3/CU co-resident), 96 blocks per XCD.
// ---------------------------------------------------------------------------
__global__ void __launch_bounds__(256, 3) mega_kernel(MP P)
{
    __shared__ __align__(16) char smem[32768];
    cg::grid_group grid = cg::this_grid();

    const int bx = blockIdx.x;
    const int b  = bx & 7;       // batch == XCD
    const int j  = bx >> 3;      // 0..95 within XCD
    const int tid = threadIdx.x;

    // P0: weight prep
    {
        const int gt = bx * 256 + tid;
        if (gt < 65536) body_cvtw(gt, P);
    }
    __threadfence();
    grid.sync();

    // P1: 32 lin tiles + 64 val tiles per XCD
    if (j < 32) {
        body_lin(smem, (b << 12) + (j << 7), P, tid);
    } else {
        const int v = j - 32;                 // 0..63
        body_val(smem, (b << 12) + ((v & 31) << 7), (v >> 5) << 7, P, tid);
    }
    __threadfence();
    grid.sync();

    // P2: gather — 512 tasks of 8 queries per XCD, grid-stride over 96 blocks
    for (int t = j; t < 512; t += 96)
        body_gather(smem, b, (b << 12) + t * 8, P, tid);
    __threadfence();
    grid.sync();

    // P3: out-proj — 64 tiles per XCD
    if (j < 64)
        body_out(smem, (b << 12) + ((j & 31) << 7), (j >> 5) << 7, P, tid);
}

// ---------------------------------------------------------------------------
// Fallback (non-cooperative) kernels — same bodies, separate launches.
// ---------------------------------------------------------------------------
__global__ __launch_bounds__(256)
void k_cvtw(MP P) { body_cvtw(blockIdx.x * 256 + threadIdx.x, P); }

__global__ __launch_bounds__(256)
void k_gemms(MP P)
{
    __shared__ __align__(16) char smem[32768];
    const int b = blockIdx.x & 7, j = blockIdx.x >> 3;
    if (j < 32) {
        body_lin(smem, (b << 12) + (j << 7), P, threadIdx.x);
    } else {
        const int v = j - 32;
        body_val(smem, (b << 12) + ((v & 31) << 7), (v >> 5) << 7, P, threadIdx.x);
    }
}

__global__ __launch_bounds__(256)
void k_gather(MP P)
{
    __shared__ __align__(16) char smem[8192];
    const int b = blockIdx.x & 7, t = blockIdx.x >> 3;
    body_gather(smem, b, (b << 12) + t * 8, P, threadIdx.x);
}

__global__ __launch_bounds__(256)
void k_out(MP P)
{
    __shared__ __align__(16) char smem[32768];
    const int b = blockIdx.x & 7, j = blockIdx.x >> 3;
    body_out(smem, (b << 12) + ((j & 31) << 7), (j >> 5) << 7, P, threadIdx.x);
}

// ---------------------------------------------------------------------------
extern "C" void kernel_launch(void* const* d_in, const int* in_sizes, int n_in,
                              void* d_out, int out_size, void* d_ws, size_t ws_size,
                              hipStream_t stream)
{
    MP P;
    P.query  = (const float*)d_in[0];
    P.value  = (const float*)d_in[1];
    P.refp   = (const float*)d_in[2];
    P.W_off  = (const float*)d_in[3];
    P.b_off  = (const float*)d_in[4];
    P.W_attn = (const float*)d_in[5];
    P.b_attn = (const float*)d_in[6];
    P.W_val  = (const float*)d_in[7];
    P.b_val  = (const float*)d_in[8];
    P.W_out  = (const float*)d_in[9];
    P.b_out  = (const float*)d_in[10];
    P.out    = (float*)d_out;

    char* ws = (char*)d_ws;
    P.projv    = (unsigned short*)ws; ws += (size_t)MTOT * 256 * 2;
    P.sampled  = (unsigned short*)ws; ws += (size_t)MTOT * 256 * 2;
    P.lin      = (float*)ws;          ws += (size_t)MTOT * 96 * 4;
    P.Wv_t     = (unsigned short*)ws; ws += 256 * 256 * 2;
    P.Wo_t     = (unsigned short*)ws; ws += 256 * 256 * 2;
    P.Wl_h     = (unsigned short*)ws; ws += 128 * 256 * 2;
    P.Wl_l     = (unsigned short*)ws; ws += 128 * 256 * 2;
    P.bias_lin = (float*)ws;          ws += 128 * 4;

    void* kargs[] = { (void*)&P };
    hipError_t e = hipLaunchCooperativeKernel((const void*)mega_kernel,
                                              dim3(768), dim3(256), kargs, 0, stream);
    if (e != hipSuccess) {
        (void)hipGetLastError();   // clear error state; use separate-kernel path
        k_cvtw  <<<dim3(256),      dim3(256), 0, stream>>>(P);
        k_gemms <<<dim3(768),      dim3(256), 0, stream>>>(P);
        k_gather<<<dim3(MTOT / 8), dim3(256), 0, stream>>>(P);
        k_out   <<<dim3(512),      dim3(256), 0, stream>>>(P);
    }
}

// Round 10
// 70.154 us; speedup vs baseline: 8.0821x; 8.0821x over previous
//
#include <hip/hip_runtime.h>
#include <math.h>

#define NHEAD 8
#define NPT 4
#define HDIM 32
#define IMG 64      // H = W = 64
#define CDIM 256
#define NQ 4096
#define BATCH 8
#define MTOT (BATCH * NQ)   // 32768

typedef __attribute__((ext_vector_type(8))) short bf16x8;
typedef __attribute__((ext_vector_type(4))) float f32x4;

__device__ __forceinline__ unsigned short f2b(float f) {
    union { float f; unsigned u; } v; v.f = f;
    unsigned r = (v.u + 0x7FFFu + ((v.u >> 16) & 1u)) >> 16;
    return (unsigned short)r;
}
__device__ __forceinline__ float b2f(unsigned short u) {
    union { unsigned u; float f; } v; v.u = ((unsigned)u) << 16;
    return v.f;
}

// XOR swizzle for [128][64]-ushort tiles (8 chunks of 16B per row).
#define SWZ(row, col)   ((col) ^ (((row) & 7) << 3))

// Async global->LDS, 16B per lane; dest = wave-uniform base + lane*16.
__device__ __forceinline__ void gload16(const void* src, void* ldsbase) {
    __builtin_amdgcn_global_load_lds(
        (const __attribute__((address_space(1))) void*)src,
        (__attribute__((address_space(3))) void*)ldsbase, 16, 0, 0);
}

// XCD pinning: XCD id = blockIdx.x & 7 == batch. Every kernel uses the same
// mapping so each XCD's L2 owns one batch's projv/lin/sampled slice.

// ---------------------------------------------------------------------------
// Weight prep.
// ---------------------------------------------------------------------------
__global__ __launch_bounds__(256)
void cvt_weights_kernel(const float* __restrict__ Wv, const float* __restrict__ Wo,
                        const float* __restrict__ Woff, const float* __restrict__ Wattn,
                        const float* __restrict__ boff, const float* __restrict__ battn,
                        unsigned short* __restrict__ Wv_t, unsigned short* __restrict__ Wo_t,
                        unsigned short* __restrict__ Wl_h, unsigned short* __restrict__ Wl_l,
                        float* __restrict__ bias_lin)
{
    int tid = blockIdx.x * 256 + threadIdx.x;   // 0 .. 65535
    int n = tid & 255, k = tid >> 8;
    Wv_t[n * 256 + k] = f2b(Wv[k * 256 + n]);
    Wo_t[n * 256 + k] = f2b(Wo[k * 256 + n]);
    if (tid < 128 * 256) {
        int nn = tid >> 8;
        int kk = tid & 255;
        float v = (nn < 64) ? Woff[kk * 64 + nn]
                : (nn < 96) ? Wattn[kk * 32 + (nn - 64)] : 0.f;
        unsigned short hi = f2b(v);
        unsigned short lo = f2b(v - b2f(hi));
        Wl_h[nn * 256 + kk] = hi;
        Wl_l[nn * 256 + kk] = lo;
    }
    if (tid < 128)
        bias_lin[tid] = (tid < 64) ? boff[tid] : (tid < 96) ? battn[tid - 64] : 0.f;
}

// ---------------------------------------------------------------------------
// Combined GEMMs, 1024 blocks (exactly 4/CU, 32 KB LDS each):
//   per XCD (= batch = bx&7), j = bx>>3 in [0,128):
//     j <  64 : value-projection tile (m = j&31, gn = (j>>5)*128), BK=64,
//               A = f32 value reg-staged cvt, B = Wv_t gload.  4 K-steps.
//     j >= 64 : lin tile K-HALF (m = u&31, kq = u>>5), BK=32, 4 K-steps,
//               A = f32 query gload + frag-time hi/lo split, B gload.
//               Writes bias-free partial lin[kq].
// ---------------------------------------------------------------------------
__global__ __launch_bounds__(256)
void fused_gemms_kernel(const float* __restrict__ value,
                        const float* __restrict__ query,
                        const unsigned short* __restrict__ Wv_t,
                        const unsigned short* __restrict__ Wl_h,
                        const unsigned short* __restrict__ Wl_l,
                        const float* __restrict__ b_val,
                        unsigned short* __restrict__ projv,
                        float* __restrict__ lin)   // [2][MTOT][96] partials
{
    __shared__ __align__(16) char smem[32768];

    const int tid  = threadIdx.x;
    const int lane = tid & 63;
    const int wid  = tid >> 6;
    const int wr = (wid >> 1) * 64;
    const int wc = (wid & 1) * 64;
    const int l15 = lane & 15;
    const int lk  = (lane >> 4) * 8;

    const int b = blockIdx.x & 7;      // batch == XCD
    const int j = blockIdx.x >> 3;     // 0..127

    f32x4 acc[4][4];
    #pragma unroll
    for (int m = 0; m < 4; ++m)
        #pragma unroll
        for (int n = 0; n < 4; ++n)
            #pragma unroll
            for (int r = 0; r < 4; ++r) acc[m][n][r] = 0.f;

    if (j < 64) {
        // ================= value projection =================
        unsigned short (*As)[64] = (unsigned short(*)[64])smem;
        unsigned short (*Bs)[64] = (unsigned short(*)[64])(smem + 16384);
        const int gm = (b << 12) + ((j & 31) << 7);
        const int gn = (j >> 5) << 7;
        const int rl  = lane >> 3;
        const int ch  = (lane & 7) ^ rl;

        for (int k0 = 0; k0 < 256; k0 += 64) {
            #pragma unroll
            for (int it = 0; it < 4; ++it) {
                const int br = it * 32 + wid * 8;
                gload16(&Wv_t[(size_t)(gn + br + rl) * 256 + k0 + ch * 8], &Bs[br][0]);
            }
            #pragma unroll
            for (int it = 0; it < 4; ++it) {
                const int chunk = it * 256 + tid;
                const int row = chunk >> 3;
                const int kc  = (chunk & 7) << 3;
                const float4* src = (const float4*)&value[(size_t)(gm + row) * 256 + k0 + kc];
                const float4 a = src[0], bb = src[1];
                float f[8] = {a.x, a.y, a.z, a.w, bb.x, bb.y, bb.z, bb.w};
                unsigned short h[8];
                #pragma unroll
                for (int jj = 0; jj < 8; ++jj) h[jj] = f2b(f[jj]);
                *(uint4*)&As[row][SWZ(row, kc)] = *(const uint4*)h;
            }
            __syncthreads();

            #pragma unroll
            for (int kk = 0; kk < 64; kk += 32) {
                bf16x8 a[4], bv[4];
                #pragma unroll
                for (int m = 0; m < 4; ++m) {
                    const int r = wr + m * 16 + l15;
                    a[m] = *(const bf16x8*)&As[r][SWZ(r, kk + lk)];
                }
                #pragma unroll
                for (int n = 0; n < 4; ++n) {
                    const int r = wc + n * 16 + l15;
                    bv[n] = *(const bf16x8*)&Bs[r][SWZ(r, kk + lk)];
                }
                #pragma unroll
                for (int m = 0; m < 4; ++m)
                    #pragma unroll
                    for (int n = 0; n < 4; ++n)
                        acc[m][n] = __builtin_amdgcn_mfma_f32_16x16x32_bf16(a[m], bv[n], acc[m][n], 0, 0, 0);
            }
            __syncthreads();
        }

        const int cr = (lane >> 4) * 4;
        #pragma unroll
        for (int n = 0; n < 4; ++n) {
            const int col = gn + wc + n * 16 + l15;
            const float bvv = b_val[col];
            #pragma unroll
            for (int m = 0; m < 4; ++m)
                #pragma unroll
                for (int r = 0; r < 4; ++r) {
                    const int row = gm + wr + m * 16 + cr + r;
                    projv[(size_t)row * 256 + col] = f2b(acc[m][n][r] + bvv);
                }
        }
    } else {
        // ====== offset/attn logits, K-half kq (BK=32, 4 K-steps) ======
        float (*Aq)[32] = (float(*)[32])smem;                              // 16 KB
        unsigned short (*Bh)[32] = (unsigned short(*)[32])(smem + 16384);  // 8 KB
        unsigned short (*Bl)[32] = (unsigned short(*)[32])(smem + 24576);  // 8 KB
        const int u  = j - 64;                 // 0..63
        const int gm = (b << 12) + ((u & 31) << 7);
        const int kq = u >> 5;                 // 0 or 1
        const int rla = lane >> 3;             // A: 8 rows x 8 chunks (16B = 4 f32)
        const int ca  = (lane & 7) ^ rla;
        const int rsb = lane >> 2;             // B: 16 rows x 4 chunks (16B = 8 us)
        const int cb  = (lane & 3) ^ (rsb & 3);

        for (int k0 = kq * 128; k0 < kq * 128 + 128; k0 += 32) {
            #pragma unroll
            for (int i = 0; i < 4; ++i) {
                const int ar = wid * 32 + i * 8;
                gload16(&query[(size_t)(gm + ar + rla) * 256 + k0 + ca * 4], &Aq[ar][0]);
            }
            #pragma unroll
            for (int i = 0; i < 2; ++i) {
                const int br = wid * 32 + i * 16;
                gload16(&Wl_h[(size_t)(br + rsb) * 256 + k0 + cb * 8], &Bh[br][0]);
                gload16(&Wl_l[(size_t)(br + rsb) * 256 + k0 + cb * 8], &Bl[br][0]);
            }
            __syncthreads();

            bf16x8 ah[4], al[4];
            #pragma unroll
            for (int m = 0; m < 4; ++m) {
                const int r = wr + m * 16 + l15;
                const int c0 = ((lk >> 2) ^ (r & 7)) << 2;
                const int c1 = (((lk >> 2) + 1) ^ (r & 7)) << 2;
                const f32x4 qa = *(const f32x4*)&Aq[r][c0];
                const f32x4 qb = *(const f32x4*)&Aq[r][c1];
                float f[8] = {qa.x, qa.y, qa.z, qa.w, qb.x, qb.y, qb.z, qb.w};
                unsigned short h[8], l[8];
                #pragma unroll
                for (int jj = 0; jj < 8; ++jj) {
                    h[jj] = f2b(f[jj]);
                    l[jj] = f2b(f[jj] - b2f(h[jj]));
                }
                ah[m] = *(const bf16x8*)h;
                al[m] = *(const bf16x8*)l;
            }

            const int nN = (wc == 0) ? 4 : 2;
            #pragma unroll
            for (int n = 0; n < 4; ++n) {
                if (n >= nN) break;
                const int r = wc + n * 16 + l15;
                const int c = ((lk >> 3) ^ (r & 3)) << 3;
                const bf16x8 bh = *(const bf16x8*)&Bh[r][c];
                const bf16x8 bl = *(const bf16x8*)&Bl[r][c];
                #pragma unroll
                for (int m = 0; m < 4; ++m) {
                    acc[m][n] = __builtin_amdgcn_mfma_f32_16x16x32_bf16(ah[m], bh, acc[m][n], 0, 0, 0);
                    acc[m][n] = __builtin_amdgcn_mfma_f32_16x16x32_bf16(ah[m], bl, acc[m][n], 0, 0, 0);
                    acc[m][n] = __builtin_amdgcn_mfma_f32_16x16x32_bf16(al[m], bh, acc[m][n], 0, 0, 0);
                }
            }
            __syncthreads();
        }

        float* dst = lin + (size_t)kq * MTOT * 96;   // bias-free partial
        const int cr = (lane >> 4) * 4;
        #pragma unroll
        for (int n = 0; n < 4; ++n) {
            const int col = wc + n * 16 + l15;
            if (col < 96) {
                #pragma unroll
                for (int m = 0; m < 4; ++m)
                    #pragma unroll
                    for (int r = 0; r < 4; ++r) {
                        const int row = gm + wr + m * 16 + cr + r;
                        dst[(size_t)row * 96 + col] = acc[m][n][r];
                    }
            }
        }
    }
}

// ---------------------------------------------------------------------------
// bf16 MFMA GEMM (out-proj): C[M x 256] = A(bf16) @ Bt^T + bias, f32 out.
// ---------------------------------------------------------------------------
__global__ __launch_bounds__(256)
void gemm_out_kernel(const unsigned short* __restrict__ Ap,
                     const unsigned short* __restrict__ Bt,
                     const float* __restrict__ bias,
                     float* __restrict__ C)
{
    __shared__ unsigned short As[128][64];
    __shared__ unsigned short Bs[128][64];

    const int tid  = threadIdx.x;
    const int lane = tid & 63;
    const int wid  = tid >> 6;
    const int gm = ((blockIdx.x & 7) << 12) + ((blockIdx.x >> 3) << 7);
    const int gn = blockIdx.y * 128;
    const int wr = (wid >> 1) * 64;
    const int wc = (wid & 1) * 64;
    const int l15 = lane & 15;
    const int lk  = (lane >> 4) * 8;
    const int rl  = lane >> 3;
    const int ch  = (lane & 7) ^ rl;

    f32x4 acc[4][4];
    #pragma unroll
    for (int m = 0; m < 4; ++m)
        #pragma unroll
        for (int n = 0; n < 4; ++n)
            #pragma unroll
            for (int r = 0; r < 4; ++r) acc[m][n][r] = 0.f;

    for (int k0 = 0; k0 < 256; k0 += 64) {
        #pragma unroll
        for (int it = 0; it < 4; ++it) {
            const int br = it * 32 + wid * 8;
            gload16(&Bt[(size_t)(gn + br + rl) * 256 + k0 + ch * 8], &Bs[br][0]);
            gload16(&Ap[(size_t)(gm + br + rl) * 256 + k0 + ch * 8], &As[br][0]);
        }
        __syncthreads();

        #pragma unroll
        for (int kk = 0; kk < 64; kk += 32) {
            bf16x8 a[4], b[4];
            #pragma unroll
            for (int m = 0; m < 4; ++m) {
                const int r = wr + m * 16 + l15;
                a[m] = *(const bf16x8*)&As[r][SWZ(r, kk + lk)];
            }
            #pragma unroll
            for (int n = 0; n < 4; ++n) {
                const int r = wc + n * 16 + l15;
                b[n] = *(const bf16x8*)&Bs[r][SWZ(r, kk + lk)];
            }
            #pragma unroll
            for (int m = 0; m < 4; ++m)
                #pragma unroll
                for (int n = 0; n < 4; ++n)
                    acc[m][n] = __builtin_amdgcn_mfma_f32_16x16x32_bf16(a[m], b[n], acc[m][n], 0, 0, 0);
        }
        __syncthreads();
    }

    const int cr = (lane >> 4) * 4;
    #pragma unroll
    for (int n = 0; n < 4; ++n) {
        const int col = gn + wc + n * 16 + l15;
        const float bv = bias[col];
        #pragma unroll
        for (int m = 0; m < 4; ++m)
            #pragma unroll
            for (int r = 0; r < 4; ++r) {
                const int row = gm + wr + m * 16 + cr + r;
                C[(size_t)row * 256 + col] = acc[m][n][r] + bv;
            }
    }
}

// ---------------------------------------------------------------------------
// Sampling: block = 8 queries (XCD-pinned batch). Phase 1: 256 threads
// (8 queries x 32 (h,p)) sum the 2 lin partials + bias, then softmax/tanh
// corner weights + packed coords. Phase 2: 2 passes, 64 lanes per query,
// uint2 gathers (4 bf16 channels/lane).
// ---------------------------------------------------------------------------
__global__ __launch_bounds__(256)
void sample_gather_kernel(const unsigned short* __restrict__ projv, // [B][4096][256] bf16
                          const float* __restrict__ lin,            // [2][M][96] partials
                          const float* __restrict__ bias_lin,       // [128]
                          const float* __restrict__ refp,           // [M][2]
                          unsigned short* __restrict__ sampled)     // [M][256] bf16
{
    __shared__ float4 s_w[8][32];
    __shared__ unsigned s_xy[8][32];

    const int i = blockIdx.x;
    const int b = i & 7;                          // batch == XCD
    const int bn0 = (b << 12) + ((i >> 3) << 3);  // first of 8 queries
    const int t = threadIdx.x;

    {
        const int sub = t >> 5;        // 0..7
        const int q = t & 31;          // h*4 + p
        const int h = q >> 2;
        const int p = q & 3;
        const int bn = bn0 + sub;
        const float2 rp = *(const float2*)&refp[(size_t)bn * 2];
        const size_t base0 = (size_t)bn * 96;
        const size_t base1 = (size_t)MTOT * 96 + base0;
        const float2 o0 = *(const float2*)&lin[base0 + h * 8 + p * 2];
        const float2 o1 = *(const float2*)&lin[base1 + h * 8 + p * 2];
        const float2 ob = *(const float2*)&bias_lin[h * 8 + p * 2];
        const float olx = o0.x + o1.x + ob.x;
        const float oly = o0.y + o1.y + ob.y;
        const float al  = lin[base0 + 64 + q] + lin[base1 + 64 + q] + bias_lin[64 + q];

        float mx = al;
        mx = fmaxf(mx, __shfl_xor(mx, 1));
        mx = fmaxf(mx, __shfl_xor(mx, 2));
        float e = expf(al - mx);
        float s = e;
        s += __shfl_xor(s, 1);
        s += __shfl_xor(s, 2);
        const float aw = e / s;

        const float lx = fminf(fmaxf(rp.x + tanhf(olx) * 0.5f, 0.f), 1.f);
        const float ly = fminf(fmaxf(rp.y + tanhf(oly) * 0.5f, 0.f), 1.f);
        const float x = lx * (float)IMG - 0.5f;
        const float y = ly * (float)IMG - 0.5f;
        const float x0f = floorf(x), y0f = floorf(y);
        const int x0 = (int)x0f, y0 = (int)y0f;
        const float wx1 = x - x0f, wx0 = 1.f - wx1;
        const float wy1 = y - y0f, wy0 = 1.f - wy1;
        const bool vx0 = (x0 >= 0), vx1 = (x0 + 1 < IMG);
        const bool vy0 = (y0 >= 0), vy1 = (y0 + 1 < IMG);
        float4 w;
        w.x = (vx0 && vy0) ? wx0 * wy0 * aw : 0.f;
        w.y = (vx1 && vy0) ? wx1 * wy0 * aw : 0.f;
        w.z = (vx0 && vy1) ? wx0 * wy1 * aw : 0.f;
        w.w = (vx1 && vy1) ? wx1 * wy1 * aw : 0.f;
        const int x0c = min(max(x0, 0), IMG - 1), x1c = min(max(x0 + 1, 0), IMG - 1);
        const int y0c = min(max(y0, 0), IMG - 1), y1c = min(max(y0 + 1, 0), IMG - 1);
        s_w[sub][q] = w;
        s_xy[sub][q] = (unsigned)x0c | ((unsigned)x1c << 8) | ((unsigned)y0c << 16) | ((unsigned)y1c << 24);
    }
    __syncthreads();

    const int l = t & 63;
    const int h2 = l >> 3;
    const int cp = l & 7;
    const unsigned short* vbase = projv + ((size_t)b << 20) + h2 * HDIM + cp * 4;

    #pragma unroll
    for (int pass = 0; pass < 2; ++pass) {
        const int sub = (t >> 6) + pass * 4;
        const int bn = bn0 + sub;

        float a0 = 0.f, a1 = 0.f, a2 = 0.f, a3 = 0.f;
        #pragma unroll
        for (int p = 0; p < 4; ++p) {
            const float4 w = s_w[sub][h2 * 4 + p];
            const unsigned xy = s_xy[sub][h2 * 4 + p];
            const int x0 = xy & 255, x1 = (xy >> 8) & 255;
            const int y0 = (xy >> 16) & 255, y1 = xy >> 24;
            const uint2 u00 = *(const uint2*)&vbase[(((y0 << 6) + x0) << 8)];
            const uint2 u01 = *(const uint2*)&vbase[(((y0 << 6) + x1) << 8)];
            const uint2 u10 = *(const uint2*)&vbase[(((y1 << 6) + x0) << 8)];
            const uint2 u11 = *(const uint2*)&vbase[(((y1 << 6) + x1) << 8)];
            a0 += w.x * b2f((unsigned short)(u00.x & 0xffff)) + w.y * b2f((unsigned short)(u01.x & 0xffff))
                + w.z * b2f((unsigned short)(u10.x & 0xffff)) + w.w * b2f((unsigned short)(u11.x & 0xffff));
            a1 += w.x * b2f((unsigned short)(u00.x >> 16)) + w.y * b2f((unsigned short)(u01.x >> 16))
                + w.z * b2f((unsigned short)(u10.x >> 16)) + w.w * b2f((unsigned short)(u11.x >> 16));
            a2 += w.x * b2f((unsigned short)(u00.y & 0xffff)) + w.y * b2f((unsigned short)(u01.y & 0xffff))
                + w.z * b2f((unsigned short)(u10.y & 0xffff)) + w.w * b2f((unsigned short)(u11.y & 0xffff));
            a3 += w.x * b2f((unsigned short)(u00.y >> 16)) + w.y * b2f((unsigned short)(u01.y >> 16))
                + w.z * b2f((unsigned short)(u10.y >> 16)) + w.w * b2f((unsigned short)(u11.y >> 16));
        }
        uint2 outp;
        outp.x = (unsigned)f2b(a0) | ((unsigned)f2b(a1) << 16);
        outp.y = (unsigned)f2b(a2) | ((unsigned)f2b(a3) << 16);
        *(uint2*)&sampled[(size_t)bn * 256 + h2 * HDIM + cp * 4] = outp;
    }
}

// ---------------------------------------------------------------------------
extern "C" void kernel_launch(void* const* d_in, const int* in_sizes, int n_in,
                              void* d_out, int out_size, void* d_ws, size_t ws_size,
                              hipStream_t stream)
{
    const float* query  = (const float*)d_in[0];
    const float* value  = (const float*)d_in[1];
    const float* refp   = (const float*)d_in[2];
    const float* W_off  = (const float*)d_in[3];
    const float* b_off  = (const float*)d_in[4];
    const float* W_attn = (const float*)d_in[5];
    const float* b_attn = (const float*)d_in[6];
    const float* W_val  = (const float*)d_in[7];
    const float* b_val  = (const float*)d_in[8];
    const float* W_out  = (const float*)d_in[9];
    const float* b_out  = (const float*)d_in[10];
    float* out = (float*)d_out;

    // workspace layout
    char* ws = (char*)d_ws;
    unsigned short* projv    = (unsigned short*)ws; ws += (size_t)MTOT * 256 * 2;
    unsigned short* sampled  = (unsigned short*)ws; ws += (size_t)MTOT * 256 * 2;
    float*          lin      = (float*)ws;          ws += (size_t)2 * MTOT * 96 * 4;
    unsigned short* Wv_t     = (unsigned short*)ws; ws += 256 * 256 * 2;
    unsigned short* Wo_t     = (unsigned short*)ws; ws += 256 * 256 * 2;
    unsigned short* Wl_h     = (unsigned short*)ws; ws += 128 * 256 * 2;
    unsigned short* Wl_l     = (unsigned short*)ws; ws += 128 * 256 * 2;
    float*          bias_lin = (float*)ws;          ws += 128 * 4;

    dim3 blk(256);

    // 1) weight prep
    cvt_weights_kernel<<<dim3(256), blk, 0, stream>>>(W_val, W_out, W_off, W_attn, b_off, b_attn,
                                                      Wv_t, Wo_t, Wl_h, Wl_l, bias_lin);

    // 2) value projection + K-split offset/attn logits (1024 blocks, 4/CU)
    fused_gemms_kernel<<<dim3(1024), blk, 0, stream>>>(value, query, Wv_t, Wl_h, Wl_l,
                                                       b_val, projv, lin);

    // 3) sampling/gather (sums lin partials + bias; XCD-pinned)
    sample_gather_kernel<<<dim3(MTOT / 8), blk, 0, stream>>>(projv, lin, bias_lin, refp, sampled);

    // 4) output projection: out = sampled @ W_out + b_out -> f32
    gemm_out_kernel<<<dim3(MTOT / 128, 2), blk, 0, stream>>>(sampled, Wo_t, b_out, out);
}

// Round 11
// 68.584 us; speedup vs baseline: 8.2671x; 1.0229x over previous
//
#include <hip/hip_runtime.h>
#include <math.h>

#define NHEAD 8
#define NPT 4
#define HDIM 32
#define IMG 64      // H = W = 64
#define CDIM 256
#define NQ 4096
#define BATCH 8
#define MTOT (BATCH * NQ)   // 32768

typedef __attribute__((ext_vector_type(8))) short bf16x8;
typedef __attribute__((ext_vector_type(4))) float f32x4;

__device__ __forceinline__ unsigned short f2b(float f) {
    union { float f; unsigned u; } v; v.f = f;
    unsigned r = (v.u + 0x7FFFu + ((v.u >> 16) & 1u)) >> 16;
    return (unsigned short)r;
}
__device__ __forceinline__ float b2f(unsigned short u) {
    union { unsigned u; float f; } v; v.u = ((unsigned)u) << 16;
    return v.f;
}

// Async global->LDS, 16B per lane; dest = wave-uniform base + lane*16.
__device__ __forceinline__ void gload16(const void* src, void* ldsbase) {
    __builtin_amdgcn_global_load_lds(
        (const __attribute__((address_space(1))) void*)src,
        (__attribute__((address_space(3))) void*)ldsbase, 16, 0, 0);
}

#define VMCNT0() asm volatile("s_waitcnt vmcnt(0)" ::: "memory")
#define VMCNT2() asm volatile("s_waitcnt vmcnt(2)" ::: "memory")
#define VMCNT4() asm volatile("s_waitcnt vmcnt(4)" ::: "memory")
#define VMCNT6() asm volatile("s_waitcnt vmcnt(6)" ::: "memory")
#define LGKM0()  asm volatile("s_waitcnt lgkmcnt(0)" ::: "memory")
#define BAR()    __builtin_amdgcn_s_barrier()
#define SCHEDB() __builtin_amdgcn_sched_barrier(0)

// XCD pinning: XCD id = blockIdx.x & 7 == batch.

// ---------------------------------------------------------------------------
// Weight prep.
// ---------------------------------------------------------------------------
__global__ __launch_bounds__(256)
void cvt_weights_kernel(const float* __restrict__ Wv, const float* __restrict__ Wo,
                        const float* __restrict__ Woff, const float* __restrict__ Wattn,
                        const float* __restrict__ boff, const float* __restrict__ battn,
                        unsigned short* __restrict__ Wv_t, unsigned short* __restrict__ Wo_t,
                        unsigned short* __restrict__ Wl_h, unsigned short* __restrict__ Wl_l,
                        float* __restrict__ bias_lin)
{
    int tid = blockIdx.x * 256 + threadIdx.x;   // 0 .. 65535
    int n = tid & 255, k = tid >> 8;
    Wv_t[n * 256 + k] = f2b(Wv[k * 256 + n]);
    Wo_t[n * 256 + k] = f2b(Wo[k * 256 + n]);
    if (tid < 128 * 256) {
        int nn = tid >> 8;
        int kk = tid & 255;
        float v = (nn < 64) ? Woff[kk * 64 + nn]
                : (nn < 96) ? Wattn[kk * 32 + (nn - 64)] : 0.f;
        unsigned short hi = f2b(v);
        unsigned short lo = f2b(v - b2f(hi));
        Wl_h[nn * 256 + kk] = hi;
        Wl_l[nn * 256 + kk] = lo;
    }
    if (tid < 128)
        bias_lin[tid] = (tid < 64) ? boff[tid] : (tid < 96) ? battn[tid - 64] : 0.f;
}

// ---------------------------------------------------------------------------
// Pipelined bf16 GEMM tile body, BK=32, double-buffered (LDS 32 KB).
// A is f32 (reg-staged cvt, early-issued loads) when A_F32, else bf16 gload.
// Counted vmcnt keeps next-stage loads in flight across barriers.
// LDS tiles [128][32] us, swizzle: phys chunk = log chunk ^ (row&3).
// ---------------------------------------------------------------------------
template<bool A_F32, bool OUT_BF16>
__device__ void gemm_pipe_body(char* smem,
                               const void* __restrict__ Ap,
                               const unsigned short* __restrict__ Bt,
                               const float* __restrict__ bias,
                               void* __restrict__ C,
                               int gm, int gn, int tid)
{
    unsigned short (*As)[128][32] = (unsigned short(*)[128][32])smem;          // 2 x 8 KB
    unsigned short (*Bs)[128][32] = (unsigned short(*)[128][32])(smem + 16384);// 2 x 8 KB

    const int lane = tid & 63, wid = tid >> 6;
    const int wr = (wid >> 1) * 64, wc = (wid & 1) * 64;
    const int l15 = lane & 15;
    const int lc  = lane >> 4;           // logical chunk 0..3 (8 ushorts each)
    const int r16 = lane >> 2;           // gload row-in-16 (0..15)
    const int cb  = (lane & 3) ^ (r16 & 3);  // pre-swizzled source chunk

    // A reg-staging geometry (A_F32): thread handles 2 chunks of 8 f32
    // chunk = it*256+tid: row = chunk>>2, kc = (chunk&3)*8
    float fa[2][8];

    f32x4 acc[4][4];
    #pragma unroll
    for (int m = 0; m < 4; ++m)
        #pragma unroll
        for (int n = 0; n < 4; ++n)
            #pragma unroll
            for (int r = 0; r < 4; ++r) acc[m][n][r] = 0.f;

    auto stageB = [&](int s, int k0) {
        #pragma unroll
        for (int i = 0; i < 2; ++i) {
            const int br = wid * 32 + i * 16;
            gload16(&Bt[(size_t)(gn + br + r16) * 256 + k0 + cb * 8], &Bs[s][br][0]);
        }
    };
    auto stageA_gl = [&](int s, int k0) {
        #pragma unroll
        for (int i = 0; i < 2; ++i) {
            const int br = wid * 32 + i * 16;
            gload16(&((const unsigned short*)Ap)[(size_t)(gm + br + r16) * 256 + k0 + cb * 8], &As[s][br][0]);
        }
    };
    auto loadA_regs = [&](int k0) {
        #pragma unroll
        for (int it = 0; it < 2; ++it) {
            const int chunk = it * 256 + tid;
            const int row = chunk >> 2;
            const int kc  = (chunk & 3) << 3;
            const float4* src = (const float4*)&((const float*)Ap)[(size_t)(gm + row) * 256 + k0 + kc];
            const float4 a = src[0], b = src[1];
            fa[it][0] = a.x; fa[it][1] = a.y; fa[it][2] = a.z; fa[it][3] = a.w;
            fa[it][4] = b.x; fa[it][5] = b.y; fa[it][6] = b.z; fa[it][7] = b.w;
        }
    };
    auto writeA = [&](int s) {
        #pragma unroll
        for (int it = 0; it < 2; ++it) {
            const int chunk = it * 256 + tid;
            const int row = chunk >> 2;
            const int kc  = (chunk & 3) << 3;
            unsigned short h[8];
            #pragma unroll
            for (int j = 0; j < 8; ++j) h[j] = f2b(fa[it][j]);
            const int pc = (((kc >> 3) ^ (row & 3)) << 3);
            *(uint4*)&As[s][row][pc] = *(const uint4*)h;
        }
    };
    auto compute = [&](int s) {
        bf16x8 a[4], b[4];
        #pragma unroll
        for (int m = 0; m < 4; ++m) {
            const int r = wr + m * 16 + l15;
            a[m] = *(const bf16x8*)&As[s][r][((lc ^ (r & 3)) << 3)];
        }
        #pragma unroll
        for (int n = 0; n < 4; ++n) {
            const int r = wc + n * 16 + l15;
            b[n] = *(const bf16x8*)&Bs[s][r][((lc ^ (r & 3)) << 3)];
        }
        #pragma unroll
        for (int m = 0; m < 4; ++m)
            #pragma unroll
            for (int n = 0; n < 4; ++n)
                acc[m][n] = __builtin_amdgcn_mfma_f32_16x16x32_bf16(a[m], b[n], acc[m][n], 0, 0, 0);
    };

    // ---- prologue: stage 0 ----
    if (A_F32) {
        loadA_regs(0);          // 4 VMEM
        stageB(0, 0);           // 2 VMEM
        VMCNT2(); SCHEDB();     // drain A regs; B(0) flying
        writeA(0);
    } else {
        stageA_gl(0, 0);        // 2 VMEM
        stageB(0, 0);           // 2 VMEM
    }

    // ---- main loop: 8 K-steps, dbuf ----
    int c = 0;
    #pragma unroll
    for (int k = 0; k < 8; ++k) {
        if (k < 7) {
            if (A_F32) loadA_regs((k + 1) * 32);    // 4 VMEM
            else       stageA_gl(c ^ 1, (k + 1) * 32);
            stageB(c ^ 1, (k + 1) * 32);            // 2 VMEM
            if (A_F32) { VMCNT6(); } else { VMCNT4(); }
        } else {
            VMCNT0();
        }
        SCHEDB();
        LGKM0();                // prior ds_writes visible (A_F32 path)
        BAR();                  // stage k ready on all waves
        compute(c);
        if (k < 7 && A_F32) {
            VMCNT2(); SCHEDB(); // drain A regs(k+1); B(k+1) flying
            writeA(c ^ 1);
        }
        LGKM0();
        BAR();                  // reads of buf[c] done before it is restaged
        c ^= 1;
    }

    // ---- epilogue ----
    const int cr = (lane >> 4) * 4;
    #pragma unroll
    for (int n = 0; n < 4; ++n) {
        const int col = gn + wc + n * 16 + l15;
        const float bv = bias[col];
        #pragma unroll
        for (int m = 0; m < 4; ++m)
            #pragma unroll
            for (int r = 0; r < 4; ++r) {
                const int row = gm + wr + m * 16 + cr + r;
                const float v = acc[m][n][r] + bv;
                if (OUT_BF16)
                    ((unsigned short*)C)[(size_t)row * 256 + col] = f2b(v);
                else
                    ((float*)C)[(size_t)row * 256 + col] = v;
            }
    }
}

// ---------------------------------------------------------------------------
// Combined GEMMs, 1024 blocks (4/CU, 32 KB LDS):
//   j <  64 : value-projection tile, pipelined dbuf body (A = f32 value)
//   j >= 64 : lin tile K-half (round-10 body, BK=32, 4 K-steps)
// ---------------------------------------------------------------------------
__global__ __launch_bounds__(256)
void fused_gemms_kernel(const float* __restrict__ value,
                        const float* __restrict__ query,
                        const unsigned short* __restrict__ Wv_t,
                        const unsigned short* __restrict__ Wl_h,
                        const unsigned short* __restrict__ Wl_l,
                        const float* __restrict__ b_val,
                        unsigned short* __restrict__ projv,
                        float* __restrict__ lin)   // [2][MTOT][96] partials
{
    __shared__ __align__(16) char smem[32768];

    const int tid  = threadIdx.x;
    const int lane = tid & 63;
    const int wid  = tid >> 6;
    const int b = blockIdx.x & 7;      // batch == XCD
    const int j = blockIdx.x >> 3;     // 0..127

    if (j < 64) {
        gemm_pipe_body<true, true>(smem, value, Wv_t, b_val, projv,
                                   (b << 12) + ((j & 31) << 7), (j >> 5) << 7, tid);
        return;
    }

    // ====== offset/attn logits, K-half kq (BK=32, 4 K-steps) ======
    const int wr = (wid >> 1) * 64;
    const int wc = (wid & 1) * 64;
    const int l15 = lane & 15;
    const int lk  = (lane >> 4) * 8;

    float (*Aq)[32] = (float(*)[32])smem;                              // 16 KB
    unsigned short (*Bh)[32] = (unsigned short(*)[32])(smem + 16384);  // 8 KB
    unsigned short (*Bl)[32] = (unsigned short(*)[32])(smem + 24576);  // 8 KB
    const int u  = j - 64;                 // 0..63
    const int gm = (b << 12) + ((u & 31) << 7);
    const int kq = u >> 5;                 // 0 or 1
    const int rla = lane >> 3;             // A: 8 rows x 8 chunks (16B = 4 f32)
    const int ca  = (lane & 7) ^ rla;
    const int rsb = lane >> 2;             // B: 16 rows x 4 chunks (16B = 8 us)
    const int cb  = (lane & 3) ^ (rsb & 3);

    f32x4 acc[4][4];
    #pragma unroll
    for (int m = 0; m < 4; ++m)
        #pragma unroll
        for (int n = 0; n < 4; ++n)
            #pragma unroll
            for (int r = 0; r < 4; ++r) acc[m][n][r] = 0.f;

    for (int k0 = kq * 128; k0 < kq * 128 + 128; k0 += 32) {
        #pragma unroll
        for (int i = 0; i < 4; ++i) {
            const int ar = wid * 32 + i * 8;
            gload16(&query[(size_t)(gm + ar + rla) * 256 + k0 + ca * 4], &Aq[ar][0]);
        }
        #pragma unroll
        for (int i = 0; i < 2; ++i) {
            const int br = wid * 32 + i * 16;
            gload16(&Wl_h[(size_t)(br + rsb) * 256 + k0 + cb * 8], &Bh[br][0]);
            gload16(&Wl_l[(size_t)(br + rsb) * 256 + k0 + cb * 8], &Bl[br][0]);
        }
        __syncthreads();

        bf16x8 ah[4], al[4];
        #pragma unroll
        for (int m = 0; m < 4; ++m) {
            const int r = wr + m * 16 + l15;
            const int c0 = ((lk >> 2) ^ (r & 7)) << 2;
            const int c1 = (((lk >> 2) + 1) ^ (r & 7)) << 2;
            const f32x4 qa = *(const f32x4*)&Aq[r][c0];
            const f32x4 qb = *(const f32x4*)&Aq[r][c1];
            float f[8] = {qa.x, qa.y, qa.z, qa.w, qb.x, qb.y, qb.z, qb.w};
            unsigned short h[8], l[8];
            #pragma unroll
            for (int jj = 0; jj < 8; ++jj) {
                h[jj] = f2b(f[jj]);
                l[jj] = f2b(f[jj] - b2f(h[jj]));
            }
            ah[m] = *(const bf16x8*)h;
            al[m] = *(const bf16x8*)l;
        }

        const int nN = (wc == 0) ? 4 : 2;
        #pragma unroll
        for (int n = 0; n < 4; ++n) {
            if (n >= nN) break;
            const int r = wc + n * 16 + l15;
            const int c = ((lk >> 3) ^ (r & 3)) << 3;
            const bf16x8 bh = *(const bf16x8*)&Bh[r][c];
            const bf16x8 bl = *(const bf16x8*)&Bl[r][c];
            #pragma unroll
            for (int m = 0; m < 4; ++m) {
                acc[m][n] = __builtin_amdgcn_mfma_f32_16x16x32_bf16(ah[m], bh, acc[m][n], 0, 0, 0);
                acc[m][n] = __builtin_amdgcn_mfma_f32_16x16x32_bf16(ah[m], bl, acc[m][n], 0, 0, 0);
                acc[m][n] = __builtin_amdgcn_mfma_f32_16x16x32_bf16(al[m], bh, acc[m][n], 0, 0, 0);
            }
        }
        __syncthreads();
    }

    float* dst = lin + (size_t)kq * MTOT * 96;   // bias-free partial
    const int cr = (lane >> 4) * 4;
    #pragma unroll
    for (int n = 0; n < 4; ++n) {
        const int col = wc + n * 16 + l15;
        if (col < 96) {
            #pragma unroll
            for (int m = 0; m < 4; ++m)
                #pragma unroll
                for (int r = 0; r < 4; ++r) {
                    const int row = gm + wr + m * 16 + cr + r;
                    dst[(size_t)row * 96 + col] = acc[m][n][r];
                }
        }
    }
}

// ---------------------------------------------------------------------------
// out-proj: pipelined dbuf body, both operands bf16 gload.
// ---------------------------------------------------------------------------
__global__ __launch_bounds__(256)
void gemm_out_kernel(const unsigned short* __restrict__ Ap,
                     const unsigned short* __restrict__ Bt,
                     const float* __restrict__ bias,
                     float* __restrict__ C)
{
    __shared__ __align__(16) char smem[32768];
    const int gm = ((blockIdx.x & 7) << 12) + ((blockIdx.x >> 3) << 7);
    const int gn = blockIdx.y * 128;
    gemm_pipe_body<false, false>(smem, Ap, Bt, bias, C, gm, gn, threadIdx.x);
}

// ---------------------------------------------------------------------------
// Sampling: block = 8 queries (XCD-pinned batch); sums 2 lin partials + bias.
// ---------------------------------------------------------------------------
__global__ __launch_bounds__(256)
void sample_gather_kernel(const unsigned short* __restrict__ projv, // [B][4096][256] bf16
                          const float* __restrict__ lin,            // [2][M][96] partials
                          const float* __restrict__ bias_lin,       // [128]
                          const float* __restrict__ refp,           // [M][2]
                          unsigned short* __restrict__ sampled)     // [M][256] bf16
{
    __shared__ float4 s_w[8][32];
    __shared__ unsigned s_xy[8][32];

    const int i = blockIdx.x;
    const int b = i & 7;                          // batch == XCD
    const int bn0 = (b << 12) + ((i >> 3) << 3);  // first of 8 queries
    const int t = threadIdx.x;

    {
        const int sub = t >> 5;        // 0..7
        const int q = t & 31;          // h*4 + p
        const int h = q >> 2;
        const int p = q & 3;
        const int bn = bn0 + sub;
        const float2 rp = *(const float2*)&refp[(size_t)bn * 2];
        const size_t base0 = (size_t)bn * 96;
        const size_t base1 = (size_t)MTOT * 96 + base0;
        const float2 o0 = *(const float2*)&lin[base0 + h * 8 + p * 2];
        const float2 o1 = *(const float2*)&lin[base1 + h * 8 + p * 2];
        const float2 ob = *(const float2*)&bias_lin[h * 8 + p * 2];
        const float olx = o0.x + o1.x + ob.x;
        const float oly = o0.y + o1.y + ob.y;
        const float al  = lin[base0 + 64 + q] + lin[base1 + 64 + q] + bias_lin[64 + q];

        float mx = al;
        mx = fmaxf(mx, __shfl_xor(mx, 1));
        mx = fmaxf(mx, __shfl_xor(mx, 2));
        float e = expf(al - mx);
        float s = e;
        s += __shfl_xor(s, 1);
        s += __shfl_xor(s, 2);
        const float aw = e / s;

        const float lx = fminf(fmaxf(rp.x + tanhf(olx) * 0.5f, 0.f), 1.f);
        const float ly = fminf(fmaxf(rp.y + tanhf(oly) * 0.5f, 0.f), 1.f);
        const float x = lx * (float)IMG - 0.5f;
        const float y = ly * (float)IMG - 0.5f;
        const float x0f = floorf(x), y0f = floorf(y);
        const int x0 = (int)x0f, y0 = (int)y0f;
        const float wx1 = x - x0f, wx0 = 1.f - wx1;
        const float wy1 = y - y0f, wy0 = 1.f - wy1;
        const bool vx0 = (x0 >= 0), vx1 = (x0 + 1 < IMG);
        const bool vy0 = (y0 >= 0), vy1 = (y0 + 1 < IMG);
        float4 w;
        w.x = (vx0 && vy0) ? wx0 * wy0 * aw : 0.f;
        w.y = (vx1 && vy0) ? wx1 * wy0 * aw : 0.f;
        w.z = (vx0 && vy1) ? wx0 * wy1 * aw : 0.f;
        w.w = (vx1 && vy1) ? wx1 * wy1 * aw : 0.f;
        const int x0c = min(max(x0, 0), IMG - 1), x1c = min(max(x0 + 1, 0), IMG - 1);
        const int y0c = min(max(y0, 0), IMG - 1), y1c = min(max(y0 + 1, 0), IMG - 1);
        s_w[sub][q] = w;
        s_xy[sub][q] = (unsigned)x0c | ((unsigned)x1c << 8) | ((unsigned)y0c << 16) | ((unsigned)y1c << 24);
    }
    __syncthreads();

    const int l = t & 63;
    const int h2 = l >> 3;
    const int cp = l & 7;
    const unsigned short* vbase = projv + ((size_t)b << 20) + h2 * HDIM + cp * 4;

    #pragma unroll
    for (int pass = 0; pass < 2; ++pass) {
        const int sub = (t >> 6) + pass * 4;
        const int bn = bn0 + sub;

        float a0 = 0.f, a1 = 0.f, a2 = 0.f, a3 = 0.f;
        #pragma unroll
        for (int p = 0; p < 4; ++p) {
            const float4 w = s_w[sub][h2 * 4 + p];
            const unsigned xy = s_xy[sub][h2 * 4 + p];
            const int x0 = xy & 255, x1 = (xy >> 8) & 255;
            const int y0 = (xy >> 16) & 255, y1 = xy >> 24;
            const uint2 u00 = *(const uint2*)&vbase[(((y0 << 6) + x0) << 8)];
            const uint2 u01 = *(const uint2*)&vbase[(((y0 << 6) + x1) << 8)];
            const uint2 u10 = *(const uint2*)&vbase[(((y1 << 6) + x0) << 8)];
            const uint2 u11 = *(const uint2*)&vbase[(((y1 << 6) + x1) << 8)];
            a0 += w.x * b2f((unsigned short)(u00.x & 0xffff)) + w.y * b2f((unsigned short)(u01.x & 0xffff))
                + w.z * b2f((unsigned short)(u10.x & 0xffff)) + w.w * b2f((unsigned short)(u11.x & 0xffff));
            a1 += w.x * b2f((unsigned short)(u00.x >> 16)) + w.y * b2f((unsigned short)(u01.x >> 16))
                + w.z * b2f((unsigned short)(u10.x >> 16)) + w.w * b2f((unsigned short)(u11.x >> 16));
            a2 += w.x * b2f((unsigned short)(u00.y & 0xffff)) + w.y * b2f((unsigned short)(u01.y & 0xffff))
                + w.z * b2f((unsigned short)(u10.y & 0xffff)) + w.w * b2f((unsigned short)(u11.y & 0xffff));
            a3 += w.x * b2f((unsigned short)(u00.y >> 16)) + w.y * b2f((unsigned short)(u01.y >> 16))
                + w.z * b2f((unsigned short)(u10.y >> 16)) + w.w * b2f((unsigned short)(u11.y >> 16));
        }
        uint2 outp;
        outp.x = (unsigned)f2b(a0) | ((unsigned)f2b(a1) << 16);
        outp.y = (unsigned)f2b(a2) | ((unsigned)f2b(a3) << 16);
        *(uint2*)&sampled[(size_t)bn * 256 + h2 * HDIM + cp * 4] = outp;
    }
}

// ---------------------------------------------------------------------------
extern "C" void kernel_launch(void* const* d_in, const int* in_sizes, int n_in,
                              void* d_out, int out_size, void* d_ws, size_t ws_size,
                              hipStream_t stream)
{
    const float* query  = (const float*)d_in[0];
    const float* value  = (const float*)d_in[1];
    const float* refp   = (const float*)d_in[2];
    const float* W_off  = (const float*)d_in[3];
    const float* b_off  = (const float*)d_in[4];
    const float* W_attn = (const float*)d_in[5];
    const float* b_attn = (const float*)d_in[6];
    const float* W_val  = (const float*)d_in[7];
    const float* b_val  = (const float*)d_in[8];
    const float* W_out  = (const float*)d_in[9];
    const float* b_out  = (const float*)d_in[10];
    float* out = (float*)d_out;

    // workspace layout
    char* ws = (char*)d_ws;
    unsigned short* projv    = (unsigned short*)ws; ws += (size_t)MTOT * 256 * 2;
    unsigned short* sampled  = (unsigned short*)ws; ws += (size_t)MTOT * 256 * 2;
    float*          lin      = (float*)ws;          ws += (size_t)2 * MTOT * 96 * 4;
    unsigned short* Wv_t     = (unsigned short*)ws; ws += 256 * 256 * 2;
    unsigned short* Wo_t     = (unsigned short*)ws; ws += 256 * 256 * 2;
    unsigned short* Wl_h     = (unsigned short*)ws; ws += 128 * 256 * 2;
    unsigned short* Wl_l     = (unsigned short*)ws; ws += 128 * 256 * 2;
    float*          bias_lin = (float*)ws;          ws += 128 * 4;

    dim3 blk(256);

    // 1) weight prep
    cvt_weights_kernel<<<dim3(256), blk, 0, stream>>>(W_val, W_out, W_off, W_attn, b_off, b_attn,
                                                      Wv_t, Wo_t, Wl_h, Wl_l, bias_lin);

    // 2) value projection (pipelined) + K-split offset/attn logits (1024 blocks)
    fused_gemms_kernel<<<dim3(1024), blk, 0, stream>>>(value, query, Wv_t, Wl_h, Wl_l,
                                                       b_val, projv, lin);

    // 3) sampling/gather (sums lin partials + bias; XCD-pinned)
    sample_gather_kernel<<<dim3(MTOT / 8), blk, 0, stream>>>(projv, lin, bias_lin, refp, sampled);

    // 4) output projection (pipelined): out = sampled @ W_out + b_out -> f32
    gemm_out_kernel<<<dim3(MTOT / 128, 2), blk, 0, stream>>>(sampled, Wo_t, b_out, out);
}